// Round 4
// baseline (446.474 us; speedup 1.0000x reference)
//
#include <hip/hip_runtime.h>

#define N_NODES 100000
#define N_EDGES 1600000
#define N_GRAPHS 512
#define NBUCK 391          // ceil(N_NODES / 256)
#define EPB 8192           // edges per block for bucket passes
#define NB_BIN ((N_EDGES + EPB - 1) / EPB)   // 196
#define CAPB 4864          // fixed slot capacity per bucket (mean 4096, sigma 64)
#define CAP 5120           // LDS staging capacity in bucket_fine

typedef _Float16 half8 __attribute__((ext_vector_type(8)));
typedef float floatx4 __attribute__((ext_vector_type(4)));

union U16 { uint4 u; half8 h; };

// ---------- CSR build ----------

__global__ __launch_bounds__(256) void init_cur(int* __restrict__ gcur) {
    int t = blockIdx.x * 256 + threadIdx.x;
    if (t < NBUCK) gcur[t] = t * CAPB;
}

__global__ __launch_bounds__(256) void bucket_scatter(const int* __restrict__ src,
                                                      const int* __restrict__ dst,
                                                      int* __restrict__ gcur,
                                                      int2* __restrict__ pairs) {
    __shared__ int cnt[NBUCK];
    __shared__ int base[NBUCK];
    int tid = threadIdx.x;
    for (int i = tid; i < NBUCK; i += 256) cnt[i] = 0;
    __syncthreads();
    int e0 = blockIdx.x * EPB, e1 = min(e0 + EPB, N_EDGES);
    for (int e = e0 + tid; e < e1; e += 256) atomicAdd(&cnt[dst[e] >> 8], 1);
    __syncthreads();
    for (int i = tid; i < NBUCK; i += 256) {
        int v = cnt[i];
        base[i] = v ? atomicAdd(&gcur[i], v) : 0;
        cnt[i] = 0;
    }
    __syncthreads();
    for (int e = e0 + tid; e < e1; e += 256) {
        int d = dst[e], b = d >> 8;
        int r = atomicAdd(&cnt[b], 1);
        pairs[base[b] + r] = make_int2(src[e], d);
    }
}

// counts = gcur[b] - b*CAPB; boff = exclusive prefix; off[N]=E
__global__ __launch_bounds__(512) void bucket_scan(const int* __restrict__ gcur,
                                                   int* __restrict__ boff,
                                                   int* __restrict__ off) {
    __shared__ int ws[8];
    int tid = threadIdx.x;
    int v = (tid < NBUCK) ? (gcur[tid] - tid * CAPB) : 0;
    int lane = tid & 63, w = tid >> 6;
    int incl = v;
    #pragma unroll
    for (int s = 1; s < 64; s <<= 1) { int y = __shfl_up(incl, s, 64); if (lane >= s) incl += y; }
    if (lane == 63) ws[w] = incl;
    __syncthreads();
    if (tid < 8) {
        int t = ws[tid];
        #pragma unroll
        for (int s = 1; s < 8; s <<= 1) { int y = __shfl_up(t, s, 64); if (tid >= s) t += y; }
        ws[tid] = t;
    }
    __syncthreads();
    int excl = (w ? ws[w - 1] : 0) + incl - v;
    if (tid < NBUCK) boff[tid] = excl;
    if (tid == NBUCK - 1) boff[NBUCK] = excl + v;
    if (tid == 0) off[N_NODES] = N_EDGES;
}

__global__ __launch_bounds__(256) void bucket_fine(const int2* __restrict__ pairs,
                                                   const int* __restrict__ boff,
                                                   int* __restrict__ off,
                                                   int* __restrict__ srclist) {
    __shared__ int ncnt[256];
    __shared__ int ws[4];
    __shared__ int stage[CAP];
    int tid = threadIdx.x, b = blockIdx.x;
    int eLo = boff[b], m = boff[b + 1] - eLo;
    int sb = b * CAPB;
    ncnt[tid] = 0;
    __syncthreads();
    for (int t = tid; t < m; t += 256) {
        int2 p = pairs[sb + t];
        atomicAdd(&ncnt[p.y & 255], 1);
    }
    __syncthreads();
    int v = ncnt[tid];
    int lane = tid & 63, w = tid >> 6;
    int incl = v;
    #pragma unroll
    for (int s = 1; s < 64; s <<= 1) { int y = __shfl_up(incl, s, 64); if (lane >= s) incl += y; }
    if (lane == 63) ws[w] = incl;
    __syncthreads();
    if (tid < 4) {
        int t = ws[tid];
        #pragma unroll
        for (int s = 1; s < 4; s <<= 1) { int y = __shfl_up(t, s, 64); if (tid >= s) t += y; }
        ws[tid] = t;
    }
    __syncthreads();
    int excl = (w ? ws[w - 1] : 0) + incl - v;
    int n = (b << 8) + tid;
    if (n < N_NODES) off[n] = eLo + excl;
    __syncthreads();
    ncnt[tid] = excl;   // cursor
    __syncthreads();
    for (int t = tid; t < m; t += 256) {
        int2 p = pairs[sb + t];
        int r = atomicAdd(&ncnt[p.y & 255], 1);
        if (r < CAP) stage[r] = p.x;
        else srclist[eLo + r] = p.x;
    }
    __syncthreads();
    int lim = m < CAP ? m : CAP;
    for (int t = tid; t < lim; t += 256) srclist[eLo + t] = stage[t];
}

// ---------- fp32 -> fp16 convert ----------
__global__ __launch_bounds__(256) void convert_f16(const float4* __restrict__ X4,
                                                   uint4* __restrict__ Xh) {
    int t = blockIdx.x * 256 + threadIdx.x;
    if (t >= N_NODES * 16) return;
    float4 a = X4[t * 2], b = X4[t * 2 + 1];
    U16 o;
    o.h[0] = (_Float16)a.x; o.h[1] = (_Float16)a.y;
    o.h[2] = (_Float16)a.z; o.h[3] = (_Float16)a.w;
    o.h[4] = (_Float16)b.x; o.h[5] = (_Float16)b.y;
    o.h[6] = (_Float16)b.z; o.h[7] = (_Float16)b.w;
    Xh[t] = o.u;
}

// ---------- pack W into MFMA B-fragment order ----------
__global__ __launch_bounds__(64) void pack_w(const float* __restrict__ W0,
                                             const float* __restrict__ W1,
                                             const float* __restrict__ W2,
                                             uint4* __restrict__ Bp) {
    int b = blockIdx.x;             // 0..95
    int layer = b >> 5;
    int r = b & 31;
    int c = r >> 3, f = r & 7;
    const float* W = (layer == 0) ? W0 : (layer == 1) ? W1 : W2;
    int l = threadIdx.x;
    int col = f * 16 + (l & 15);
    int k0 = c * 32 + (l >> 4) * 8;
    U16 o;
    #pragma unroll
    for (int j = 0; j < 8; ++j) o.h[j] = (_Float16)W[col * 128 + k0 + j];
    Bp[layer * 2048 + (c * 8 + f) * 64 + l] = o.u;
}

// ---------- fused GIN layer: H[n] = act((X[n] + sum_j X[src_j]) @ W.T + b) ----------
// 256 threads = 4 waves, 128 rows/block. Phase 1: 16-lane groups aggregate rows
// into LDS (row stride 272 B -> bank shift +4/row, <=2-way conflicts). Phase 2: MFMA.
#define LDSW 136   // ushorts per row (272 B)

__global__ __launch_bounds__(256) void gin_layer(const uint4* __restrict__ X4,
                                                 const uint4* __restrict__ Bp,
                                                 const float* __restrict__ bias,
                                                 _Float16* __restrict__ H,
                                                 const int* __restrict__ off,
                                                 const int* __restrict__ srclist,
                                                 int doRelu) {
    __shared__ ushort lds[128 * LDSW];
    int tid = threadIdx.x;
    int g = tid >> 4;        // group 0..15
    int c = tid & 15;        // 16-B chunk within row
    int n0 = blockIdx.x * 128;

    // phase 1: aggregate 8 rows per group
    #pragma unroll 1
    for (int rr = 0; rr < 8; ++rr) {
        int r = g * 8 + rr;
        int nc = min(n0 + r, N_NODES - 1);
        int j0 = off[nc], j1 = off[nc + 1];
        U16 a; a.u = X4[(size_t)nc * 16 + c];
        half8 acc = a.h;
        int j = j0;
        for (; j + 8 <= j1; j += 8) {
            int s0 = srclist[j],     s1 = srclist[j + 1], s2 = srclist[j + 2], s3 = srclist[j + 3];
            int s4 = srclist[j + 4], s5 = srclist[j + 5], s6 = srclist[j + 6], s7 = srclist[j + 7];
            U16 v0, v1, v2, v3, v4, v5, v6, v7;
            v0.u = X4[(size_t)s0 * 16 + c];
            v1.u = X4[(size_t)s1 * 16 + c];
            v2.u = X4[(size_t)s2 * 16 + c];
            v3.u = X4[(size_t)s3 * 16 + c];
            v4.u = X4[(size_t)s4 * 16 + c];
            v5.u = X4[(size_t)s5 * 16 + c];
            v6.u = X4[(size_t)s6 * 16 + c];
            v7.u = X4[(size_t)s7 * 16 + c];
            acc += v0.h; acc += v1.h; acc += v2.h; acc += v3.h;
            acc += v4.h; acc += v5.h; acc += v6.h; acc += v7.h;
        }
        for (; j < j1; ++j) {
            U16 v; v.u = X4[(size_t)srclist[j] * 16 + c];
            acc += v.h;
        }
        U16 o; o.h = acc;
        *(uint4*)&lds[r * LDSW + c * 8] = o.u;
    }
    __syncthreads();

    // phase 2: MFMA, wave w owns rows [w*32, w*32+32)
    int wid = tid >> 6, lane = tid & 63;
    int rbase = wid * 32;
    int lrow = lane & 15;
    int lk = (lane >> 4) * 8;

    floatx4 acc2[2][8];
    #pragma unroll
    for (int r = 0; r < 2; ++r)
        #pragma unroll
        for (int f = 0; f < 8; ++f) acc2[r][f] = (floatx4)0.f;

    #pragma unroll
    for (int c4 = 0; c4 < 4; ++c4) {
        U16 a0, a1;
        a0.u = *(const uint4*)&lds[(rbase + lrow) * LDSW + c4 * 32 + lk];
        a1.u = *(const uint4*)&lds[(rbase + 16 + lrow) * LDSW + c4 * 32 + lk];
        #pragma unroll
        for (int f = 0; f < 8; ++f) {
            U16 b; b.u = Bp[(c4 * 8 + f) * 64 + lane];
            acc2[0][f] = __builtin_amdgcn_mfma_f32_16x16x32_f16(a0.h, b.h, acc2[0][f], 0, 0, 0);
            acc2[1][f] = __builtin_amdgcn_mfma_f32_16x16x32_f16(a1.h, b.h, acc2[1][f], 0, 0, 0);
        }
    }

    int colb = lane & 15;
    int rq = (lane >> 4) * 4;
    #pragma unroll
    for (int f = 0; f < 8; ++f) {
        float bv = bias[f * 16 + colb];
        #pragma unroll
        for (int r = 0; r < 2; ++r) {
            #pragma unroll
            for (int q = 0; q < 4; ++q) {
                int row = n0 + rbase + r * 16 + rq + q;
                if (row < N_NODES) {
                    float v = acc2[r][f][q] + bv;
                    if (doRelu) v = fmaxf(v, 0.f);
                    H[(size_t)row * 128 + f * 16 + colb] = (_Float16)v;
                }
            }
        }
    }
}

// ---------- pooling + classifier ----------
__device__ __forceinline__ int lower_bound_i(const int* a, int n, int val) {
    int lo = 0, hi = n;
    while (lo < hi) {
        int mid = (lo + hi) >> 1;
        if (a[mid] < val) lo = mid + 1; else hi = mid;
    }
    return lo;
}

__global__ __launch_bounds__(256) void pool_kernel(const uint4* __restrict__ Hh,
                                                   const int* __restrict__ batch,
                                                   const float* __restrict__ Wg,
                                                   const float* __restrict__ bg,
                                                   float* __restrict__ out) {
    __shared__ float p[16 * 128];
    __shared__ float pooled[128];
    int g = blockIdx.x, tid = threadIdx.x;
    int c = tid & 15, r = tid >> 4;
    int lo = lower_bound_i(batch, N_NODES, g);
    int hi = lower_bound_i(batch, N_NODES, g + 1);
    float acc[8] = {0, 0, 0, 0, 0, 0, 0, 0};
    for (int i = lo + r; i < hi; i += 16) {
        U16 v; v.u = Hh[i * 16 + c];
        #pragma unroll
        for (int k = 0; k < 8; ++k) acc[k] += (float)v.h[k];
    }
    #pragma unroll
    for (int k = 0; k < 8; ++k) p[r * 128 + c * 8 + k] = acc[k];
    __syncthreads();
    if (tid < 128) {
        float s = 0.f;
        #pragma unroll
        for (int q = 0; q < 16; ++q) s += p[q * 128 + tid];
        pooled[tid] = s / fmaxf((float)(hi - lo), 1.0f);
    }
    __syncthreads();
    if (tid < 10) {
        float s = bg[tid];
        #pragma unroll 4
        for (int k = 0; k < 128; ++k) s += pooled[k] * Wg[tid * 128 + k];
        out[g * 10 + tid] = s;
    }
}

// ---------- launch ----------
extern "C" void kernel_launch(void* const* d_in, const int* in_sizes, int n_in,
                              void* d_out, int out_size, void* d_ws, size_t ws_size,
                              hipStream_t stream) {
    const float* x   = (const float*)d_in[0];
    const int*   ei  = (const int*)d_in[1];
    const int*   bat = (const int*)d_in[2];
    const float* W0  = (const float*)d_in[3];
    const float* b0  = (const float*)d_in[4];
    const float* W1  = (const float*)d_in[5];
    const float* b1  = (const float*)d_in[6];
    const float* W2  = (const float*)d_in[7];
    const float* b2  = (const float*)d_in[8];
    const float* Wg  = (const float*)d_in[9];
    const float* bg  = (const float*)d_in[10];
    float* out = (float*)d_out;

    const int* src = ei;
    const int* dst = ei + N_EDGES;

    char* w = (char*)d_ws;
    _Float16* P0 = (_Float16*)(w);                  // 25,600,000 B (X mirror; later H2)
    _Float16* P1 = (_Float16*)(w + 25600000);       // 25,600,000 B (H0)
    _Float16* P2 = (_Float16*)(w + 51200000);       // 25,600,000 B (H1)
    int2*   pairs   = (int2*)(w + 25600000);        // aliases P1 during CSR build (15.2 MB)
    int*    srclist = (int*)(w + 76800000);         // 6,400,000 B
    int*    off     = (int*)(w + 83200000);         // 400,016 B
    uint4*  Bp      = (uint4*)(w + 83700000);       // 98,304 B
    int*    gcur    = (int*)(w + 83900000);         // NBUCK ints
    int*    boff    = gcur + NBUCK + 1;             // NBUCK+1 ints

    // CSR build (pairs region is free until gin_layer writes P1)
    init_cur<<<2, 256, 0, stream>>>(gcur);
    bucket_scatter<<<NB_BIN, 256, 0, stream>>>(src, dst, gcur, pairs);
    bucket_scan<<<1, 512, 0, stream>>>(gcur, boff, off);
    bucket_fine<<<NBUCK, 256, 0, stream>>>(pairs, boff, off, srclist);

    // input -> fp16 mirror; weights -> fragment-packed fp16
    convert_f16<<<(N_NODES * 16 + 255) / 256, 256, 0, stream>>>((const float4*)x, (uint4*)P0);
    pack_w<<<96, 64, 0, stream>>>(W0, W1, W2, Bp);

    int grid = (N_NODES + 127) / 128;
    // layer 0: P0 -> P1
    gin_layer<<<grid, 256, 0, stream>>>((const uint4*)P0, Bp, b0, P1, off, srclist, 1);
    // layer 1: P1 -> P2
    gin_layer<<<grid, 256, 0, stream>>>((const uint4*)P1, Bp + 2048, b1, P2, off, srclist, 1);
    // layer 2: P2 -> P0
    gin_layer<<<grid, 256, 0, stream>>>((const uint4*)P2, Bp + 4096, b2, P0, off, srclist, 0);

    // pool + classifier
    pool_kernel<<<N_GRAPHS, 256, 0, stream>>>((const uint4*)P0, bat, Wg, bg, out);
}

// Round 5
// 332.130 us; speedup vs baseline: 1.3443x; 1.3443x over previous
//
#include <hip/hip_runtime.h>

#define N_NODES 100000
#define N_EDGES 1600000
#define N_GRAPHS 512
#define NBUCK 391          // ceil(N_NODES / 256)
#define EPB 8192           // edges per block for bucket passes
#define NB_BIN ((N_EDGES + EPB - 1) / EPB)   // 196
#define CAPB 4864          // fixed slot capacity per bucket (mean 4096, sigma 64)
#define CAP 5120           // LDS staging capacity in bucket_fine

typedef _Float16 half8 __attribute__((ext_vector_type(8)));
typedef float floatx4 __attribute__((ext_vector_type(4)));

union U16 { uint4 u; half8 h; };

// ---------- CSR build ----------

__global__ __launch_bounds__(256) void init_cur(int* __restrict__ gcur) {
    int t = blockIdx.x * 256 + threadIdx.x;
    if (t < NBUCK) gcur[t] = t * CAPB;
}

// pairs entry: src (bits 0..16) | (dst&255) << 17
__global__ __launch_bounds__(256) void bucket_scatter(const int* __restrict__ src,
                                                      const int* __restrict__ dst,
                                                      int* __restrict__ gcur,
                                                      unsigned* __restrict__ pairs) {
    __shared__ int cnt[NBUCK];
    __shared__ int base[NBUCK];
    int tid = threadIdx.x;
    for (int i = tid; i < NBUCK; i += 256) cnt[i] = 0;
    __syncthreads();
    int e0 = blockIdx.x * EPB, e1 = min(e0 + EPB, N_EDGES);
    for (int e = e0 + tid; e < e1; e += 256) atomicAdd(&cnt[dst[e] >> 8], 1);
    __syncthreads();
    for (int i = tid; i < NBUCK; i += 256) {
        int v = cnt[i];
        base[i] = v ? atomicAdd(&gcur[i], v) : 0;
        cnt[i] = 0;
    }
    __syncthreads();
    for (int e = e0 + tid; e < e1; e += 256) {
        int d = dst[e], b = d >> 8;
        int r = atomicAdd(&cnt[b], 1);
        pairs[base[b] + r] = (unsigned)src[e] | ((unsigned)(d & 255) << 17);
    }
}

// counts = gcur[b] - b*CAPB; boff = exclusive prefix; off[N]=E
__global__ __launch_bounds__(512) void bucket_scan(const int* __restrict__ gcur,
                                                   int* __restrict__ boff,
                                                   int* __restrict__ off) {
    __shared__ int ws[8];
    int tid = threadIdx.x;
    int v = (tid < NBUCK) ? (gcur[tid] - tid * CAPB) : 0;
    int lane = tid & 63, w = tid >> 6;
    int incl = v;
    #pragma unroll
    for (int s = 1; s < 64; s <<= 1) { int y = __shfl_up(incl, s, 64); if (lane >= s) incl += y; }
    if (lane == 63) ws[w] = incl;
    __syncthreads();
    if (tid < 8) {
        int t = ws[tid];
        #pragma unroll
        for (int s = 1; s < 8; s <<= 1) { int y = __shfl_up(t, s, 64); if (tid >= s) t += y; }
        ws[tid] = t;
    }
    __syncthreads();
    int excl = (w ? ws[w - 1] : 0) + incl - v;
    if (tid < NBUCK) boff[tid] = excl;
    if (tid == NBUCK - 1) boff[NBUCK] = excl + v;
    if (tid == 0) off[N_NODES] = N_EDGES;
}

__global__ __launch_bounds__(256) void bucket_fine(const unsigned* __restrict__ pairs,
                                                   const int* __restrict__ boff,
                                                   int* __restrict__ off,
                                                   int* __restrict__ srclist) {
    __shared__ int ncnt[256];
    __shared__ int ws[4];
    __shared__ int stage[CAP];
    int tid = threadIdx.x, b = blockIdx.x;
    int eLo = boff[b], m = boff[b + 1] - eLo;
    int sb = b * CAPB;
    ncnt[tid] = 0;
    __syncthreads();
    for (int t = tid; t < m; t += 256) {
        unsigned p = pairs[sb + t];
        atomicAdd(&ncnt[(p >> 17) & 255], 1);
    }
    __syncthreads();
    int v = ncnt[tid];
    int lane = tid & 63, w = tid >> 6;
    int incl = v;
    #pragma unroll
    for (int s = 1; s < 64; s <<= 1) { int y = __shfl_up(incl, s, 64); if (lane >= s) incl += y; }
    if (lane == 63) ws[w] = incl;
    __syncthreads();
    if (tid < 4) {
        int t = ws[tid];
        #pragma unroll
        for (int s = 1; s < 4; s <<= 1) { int y = __shfl_up(t, s, 64); if (tid >= s) t += y; }
        ws[tid] = t;
    }
    __syncthreads();
    int excl = (w ? ws[w - 1] : 0) + incl - v;
    int n = (b << 8) + tid;
    if (n < N_NODES) off[n] = eLo + excl;
    __syncthreads();
    ncnt[tid] = excl;   // cursor
    __syncthreads();
    for (int t = tid; t < m; t += 256) {
        unsigned p = pairs[sb + t];
        int r = atomicAdd(&ncnt[(p >> 17) & 255], 1);
        int s = (int)(p & 0x1FFFFu);
        if (r < CAP) stage[r] = s;
        else srclist[eLo + r] = s;
    }
    __syncthreads();
    int lim = m < CAP ? m : CAP;
    for (int t = tid; t < lim; t += 256) srclist[eLo + t] = stage[t];
}

// ---------- fp32 -> fp16 convert ----------
__global__ __launch_bounds__(256) void convert_f16(const float4* __restrict__ X4,
                                                   uint4* __restrict__ Xh) {
    int t = blockIdx.x * 256 + threadIdx.x;
    if (t >= N_NODES * 16) return;
    float4 a = X4[t * 2], b = X4[t * 2 + 1];
    U16 o;
    o.h[0] = (_Float16)a.x; o.h[1] = (_Float16)a.y;
    o.h[2] = (_Float16)a.z; o.h[3] = (_Float16)a.w;
    o.h[4] = (_Float16)b.x; o.h[5] = (_Float16)b.y;
    o.h[6] = (_Float16)b.z; o.h[7] = (_Float16)b.w;
    Xh[t] = o.u;
}

// ---------- pack W into MFMA B-fragment order ----------
// Bpack[layer][c(4)][f(8)][lane(64)][j(8)] = W[f*16 + (lane&15)][c*32 + (lane>>4)*8 + j]
__global__ __launch_bounds__(64) void pack_w(const float* __restrict__ W0,
                                             const float* __restrict__ W1,
                                             const float* __restrict__ W2,
                                             uint4* __restrict__ Bp) {
    int b = blockIdx.x;             // 0..95
    int layer = b >> 5;
    int r = b & 31;
    int c = r >> 3, f = r & 7;
    const float* W = (layer == 0) ? W0 : (layer == 1) ? W1 : W2;
    int l = threadIdx.x;
    int col = f * 16 + (l & 15);
    int k0 = c * 32 + (l >> 4) * 8;
    U16 o;
    #pragma unroll
    for (int j = 0; j < 8; ++j) o.h[j] = (_Float16)W[col * 128 + k0 + j];
    Bp[layer * 2048 + (c * 8 + f) * 64 + l] = o.u;
}

// ---------- fused GIN layer, 64-row tile ----------
// 256 threads = 4 waves, 64 rows/block, grid 1563 (~6 blocks/CU; LDS 17.4 KB -> 8/CU cap).
// Phase 1: 16 groups x 4 rows aggregate into LDS (row stride 272 B, <=2-way conflicts).
// Phase 2: wave w MFMAs rows [w*16, w*16+16) x 128 cols (32 MFMAs, acc 32 VGPR).
#define LDSW 136   // ushorts per row (272 B)

__global__ __launch_bounds__(256) void gin_layer(const uint4* __restrict__ X4,
                                                 const uint4* __restrict__ Bp,
                                                 const float* __restrict__ bias,
                                                 _Float16* __restrict__ H,
                                                 const int* __restrict__ off,
                                                 const int* __restrict__ srclist,
                                                 int doRelu) {
    __shared__ ushort lds[64 * LDSW];
    int tid = threadIdx.x;
    int g = tid >> 4;        // group 0..15
    int c = tid & 15;        // 16-B chunk within row
    int n0 = blockIdx.x * 64;

    // phase 1: aggregate 4 rows per group
    #pragma unroll 1
    for (int rr = 0; rr < 4; ++rr) {
        int r = g * 4 + rr;
        int nc = min(n0 + r, N_NODES - 1);
        int j0 = off[nc], j1 = off[nc + 1];
        U16 a; a.u = X4[(size_t)nc * 16 + c];
        half8 acc = a.h;
        int j = j0;
        for (; j + 8 <= j1; j += 8) {
            int s0 = srclist[j],     s1 = srclist[j + 1], s2 = srclist[j + 2], s3 = srclist[j + 3];
            int s4 = srclist[j + 4], s5 = srclist[j + 5], s6 = srclist[j + 6], s7 = srclist[j + 7];
            U16 v0, v1, v2, v3, v4, v5, v6, v7;
            v0.u = X4[(size_t)s0 * 16 + c];
            v1.u = X4[(size_t)s1 * 16 + c];
            v2.u = X4[(size_t)s2 * 16 + c];
            v3.u = X4[(size_t)s3 * 16 + c];
            v4.u = X4[(size_t)s4 * 16 + c];
            v5.u = X4[(size_t)s5 * 16 + c];
            v6.u = X4[(size_t)s6 * 16 + c];
            v7.u = X4[(size_t)s7 * 16 + c];
            acc += v0.h; acc += v1.h; acc += v2.h; acc += v3.h;
            acc += v4.h; acc += v5.h; acc += v6.h; acc += v7.h;
        }
        for (; j < j1; ++j) {
            U16 v; v.u = X4[(size_t)srclist[j] * 16 + c];
            acc += v.h;
        }
        U16 o; o.h = acc;
        *(uint4*)&lds[r * LDSW + c * 8] = o.u;
    }
    __syncthreads();

    // phase 2: wave w owns rows [w*16, w*16+16)
    int wid = tid >> 6, lane = tid & 63;
    int rbase = wid * 16;
    int lrow = lane & 15;
    int lk = (lane >> 4) * 8;

    floatx4 acc2[8];
    #pragma unroll
    for (int f = 0; f < 8; ++f) acc2[f] = (floatx4)0.f;

    #pragma unroll
    for (int c4 = 0; c4 < 4; ++c4) {
        U16 a0;
        a0.u = *(const uint4*)&lds[(rbase + lrow) * LDSW + c4 * 32 + lk];
        #pragma unroll
        for (int f = 0; f < 8; ++f) {
            U16 b; b.u = Bp[(c4 * 8 + f) * 64 + lane];
            acc2[f] = __builtin_amdgcn_mfma_f32_16x16x32_f16(a0.h, b.h, acc2[f], 0, 0, 0);
        }
    }

    int colb = lane & 15;
    int rq = (lane >> 4) * 4;
    #pragma unroll
    for (int f = 0; f < 8; ++f) {
        float bv = bias[f * 16 + colb];
        #pragma unroll
        for (int q = 0; q < 4; ++q) {
            int row = n0 + rbase + rq + q;
            if (row < N_NODES) {
                float v = acc2[f][q] + bv;
                if (doRelu) v = fmaxf(v, 0.f);
                H[(size_t)row * 128 + f * 16 + colb] = (_Float16)v;
            }
        }
    }
}

// ---------- pooling + classifier ----------
__device__ __forceinline__ int lower_bound_i(const int* a, int n, int val) {
    int lo = 0, hi = n;
    while (lo < hi) {
        int mid = (lo + hi) >> 1;
        if (a[mid] < val) lo = mid + 1; else hi = mid;
    }
    return lo;
}

__global__ __launch_bounds__(256) void pool_kernel(const uint4* __restrict__ Hh,
                                                   const int* __restrict__ batch,
                                                   const float* __restrict__ Wg,
                                                   const float* __restrict__ bg,
                                                   float* __restrict__ out) {
    __shared__ float p[16 * 128];
    __shared__ float pooled[128];
    int g = blockIdx.x, tid = threadIdx.x;
    int c = tid & 15, r = tid >> 4;
    int lo = lower_bound_i(batch, N_NODES, g);
    int hi = lower_bound_i(batch, N_NODES, g + 1);
    float acc[8] = {0, 0, 0, 0, 0, 0, 0, 0};
    for (int i = lo + r; i < hi; i += 16) {
        U16 v; v.u = Hh[i * 16 + c];
        #pragma unroll
        for (int k = 0; k < 8; ++k) acc[k] += (float)v.h[k];
    }
    #pragma unroll
    for (int k = 0; k < 8; ++k) p[r * 128 + c * 8 + k] = acc[k];
    __syncthreads();
    if (tid < 128) {
        float s = 0.f;
        #pragma unroll
        for (int q = 0; q < 16; ++q) s += p[q * 128 + tid];
        pooled[tid] = s / fmaxf((float)(hi - lo), 1.0f);
    }
    __syncthreads();
    if (tid < 10) {
        float s = bg[tid];
        #pragma unroll 4
        for (int k = 0; k < 128; ++k) s += pooled[k] * Wg[tid * 128 + k];
        out[g * 10 + tid] = s;
    }
}

// ---------- launch ----------
extern "C" void kernel_launch(void* const* d_in, const int* in_sizes, int n_in,
                              void* d_out, int out_size, void* d_ws, size_t ws_size,
                              hipStream_t stream) {
    const float* x   = (const float*)d_in[0];
    const int*   ei  = (const int*)d_in[1];
    const int*   bat = (const int*)d_in[2];
    const float* W0  = (const float*)d_in[3];
    const float* b0  = (const float*)d_in[4];
    const float* W1  = (const float*)d_in[5];
    const float* b1  = (const float*)d_in[6];
    const float* W2  = (const float*)d_in[7];
    const float* b2  = (const float*)d_in[8];
    const float* Wg  = (const float*)d_in[9];
    const float* bg  = (const float*)d_in[10];
    float* out = (float*)d_out;

    const int* src = ei;
    const int* dst = ei + N_EDGES;

    char* w = (char*)d_ws;
    _Float16* P0 = (_Float16*)(w);                  // 25,600,000 B (X mirror; later H2)
    _Float16* P1 = (_Float16*)(w + 25600000);       // 25,600,000 B (H0)
    _Float16* P2 = (_Float16*)(w + 51200000);       // 25,600,000 B (H1)
    unsigned* pairs = (unsigned*)(w + 25600000);    // aliases P1 during CSR build (7.6 MB)
    int*    srclist = (int*)(w + 76800000);         // 6,400,000 B
    int*    off     = (int*)(w + 83200000);         // 400,016 B
    uint4*  Bp      = (uint4*)(w + 83700000);       // 98,304 B
    int*    gcur    = (int*)(w + 83900000);         // NBUCK ints
    int*    boff    = gcur + NBUCK + 1;             // NBUCK+1 ints

    // CSR build (pairs region is free until gin_layer writes P1)
    init_cur<<<2, 256, 0, stream>>>(gcur);
    bucket_scatter<<<NB_BIN, 256, 0, stream>>>(src, dst, gcur, pairs);
    bucket_scan<<<1, 512, 0, stream>>>(gcur, boff, off);
    bucket_fine<<<NBUCK, 256, 0, stream>>>(pairs, boff, off, srclist);

    // input -> fp16 mirror; weights -> fragment-packed fp16
    convert_f16<<<(N_NODES * 16 + 255) / 256, 256, 0, stream>>>((const float4*)x, (uint4*)P0);
    pack_w<<<96, 64, 0, stream>>>(W0, W1, W2, Bp);

    int grid = (N_NODES + 63) / 64;   // 1563
    // layer 0: P0 -> P1
    gin_layer<<<grid, 256, 0, stream>>>((const uint4*)P0, Bp, b0, P1, off, srclist, 1);
    // layer 1: P1 -> P2
    gin_layer<<<grid, 256, 0, stream>>>((const uint4*)P1, Bp + 2048, b1, P2, off, srclist, 1);
    // layer 2: P2 -> P0
    gin_layer<<<grid, 256, 0, stream>>>((const uint4*)P2, Bp + 4096, b2, P0, off, srclist, 0);

    // pool + classifier
    pool_kernel<<<N_GRAPHS, 256, 0, stream>>>((const uint4*)P0, bat, Wg, bg, out);
}